// Round 1
// baseline (455.784 us; speedup 1.0000x reference)
//
#include <hip/hip_runtime.h>
#include <math.h>

#define T_ 30
#define C_ 512
#define N_ 784   // 28*28
#define K_ 64
#define EPSV 1e-12f

__device__ __forceinline__ float wave_sum(float v) {
    #pragma unroll
    for (int m = 32; m >= 1; m >>= 1) v += __shfl_xor(v, m, 64);
    return v;
}
__device__ __forceinline__ float wave_max(float v) {
    #pragma unroll
    for (int m = 32; m >= 1; m >>= 1) v = fmaxf(v, __shfl_xor(v, m, 64));
    return v;
}

// wT[c][k] = w[k][c]  (so lane=k reads are coalesced)
__global__ void k_transpose_w(const float* __restrict__ w, float* __restrict__ wT) {
    int idx = blockIdx.x * 256 + threadIdx.x;  // 0..32767, k*512+c
    int k = idx >> 9, c = idx & 511;
    wT[c * 64 + k] = w[idx];
}

// invn[t][n] = 1 / max(||x[t,:,n]||, eps)
__global__ void k_invnorm(const float* __restrict__ x, float* __restrict__ invn) {
    int t = blockIdx.y;
    int n = blockIdx.x * 256 + threadIdx.x;
    if (n >= N_) return;
    const float* xp = x + (size_t)t * C_ * N_ + n;
    float s = 0.f;
    #pragma unroll 8
    for (int c = 0; c < C_; ++c) { float v = xp[(size_t)c * N_]; s = fmaf(v, v, s); }
    invn[t * N_ + n] = 1.0f / fmaxf(sqrtf(s), EPSV);
}

// logits[t,k,n] = invn*(wT^T x) + b ; softmax over k ; a stored [t][n][k]
__global__ __launch_bounds__(256) void k_assign(
    const float* __restrict__ x, const float* __restrict__ wT,
    const float* __restrict__ b, const float* __restrict__ invn,
    float* __restrict__ a)
{
    __shared__ float sx[64 * 64];   // [c][n]  (also reused for logits [n][k])
    __shared__ float sw[64 * 64];   // [c][k]
    int t = blockIdx.y;
    int n0 = blockIdx.x * 64;
    int tid = threadIdx.x;
    int nl = tid & 63, kg = tid >> 6;   // wave kg, lane nl
    float acc[16];
    #pragma unroll
    for (int i = 0; i < 16; ++i) acc[i] = 0.f;

    for (int cc = 0; cc < C_; cc += 64) {
        #pragma unroll
        for (int i = 0; i < 16; ++i) {
            int f = tid + i * 256;
            sw[f] = wT[cc * 64 + f];
            int c = f >> 6, n = f & 63;
            sx[f] = (n0 + n < N_) ? x[((size_t)t * C_ + cc + c) * N_ + n0 + n] : 0.f;
        }
        __syncthreads();
        for (int c = 0; c < 64; ++c) {
            float xv = sx[c * 64 + nl];
            const float4* wp = reinterpret_cast<const float4*>(&sw[c * 64 + kg * 16]);
            #pragma unroll
            for (int j = 0; j < 4; ++j) {
                float4 w4 = wp[j];
                acc[j*4+0] = fmaf(w4.x, xv, acc[j*4+0]);
                acc[j*4+1] = fmaf(w4.y, xv, acc[j*4+1]);
                acc[j*4+2] = fmaf(w4.z, xv, acc[j*4+2]);
                acc[j*4+3] = fmaf(w4.w, xv, acc[j*4+3]);
            }
        }
        __syncthreads();
    }
    // logits -> LDS as [n][k]
    float iv = (n0 + nl < N_) ? invn[t * N_ + n0 + nl] : 0.f;
    #pragma unroll
    for (int i = 0; i < 16; ++i) {
        float lg = fmaf(acc[i], iv, b[kg * 16 + i]);
        sx[nl * 64 + kg * 16 + i] = lg;
    }
    __syncthreads();
    // softmax over k: wave kg handles n = kg*16 .. +15, lane = k
    int lane = tid & 63;
    for (int nn = 0; nn < 16; ++nn) {
        int n_l = kg * 16 + nn;
        float v = sx[n_l * 64 + lane];
        float m = wave_max(v);
        float e = __expf(v - m);
        float s = wave_sum(e);
        float av = e / s;
        if (n0 + n_l < N_) a[((size_t)t * N_ + n0 + n_l) * K_ + lane] = av;
    }
}

// asum[t][k] = sum_n a[t][n][k]
__global__ void k_asum(const float* __restrict__ a, float* __restrict__ asum) {
    int t = blockIdx.x;
    int tid = threadIdx.x;
    int k = tid & 63, g = tid >> 6;
    float s = 0.f;
    for (int n = g; n < N_; n += 4)
        s += a[((size_t)t * N_ + n) * K_ + k];
    __shared__ float red[4][64];
    red[g][k] = s;
    __syncthreads();
    if (tid < 64)
        asum[t * 64 + tid] = red[0][tid] + red[1][tid] + red[2][tid] + red[3][tid];
}

// vlad[t][k][c] = sum_n (a*invn)[t,k,n]*x[t,c,n] - asum[t,k]*cent[k,c]
__global__ __launch_bounds__(256) void k_vlad(
    const float* __restrict__ x, const float* __restrict__ a,
    const float* __restrict__ invn, const float* __restrict__ asum,
    const float* __restrict__ cent, float* __restrict__ vlad)
{
    __shared__ float sa[64 * 64];      // [n][k]
    __shared__ float sx[64 * 65];      // [c][n] padded
    int t = blockIdx.y;
    int c0 = blockIdx.x * 64;
    int tid = threadIdx.x;
    int cl = tid & 63, kg = tid >> 6;
    float acc[16];
    #pragma unroll
    for (int i = 0; i < 16; ++i) acc[i] = 0.f;

    for (int nc = 0; nc < N_; nc += 64) {
        #pragma unroll
        for (int i = 0; i < 16; ++i) {
            int f = tid + i * 256;
            int n = f >> 6, k = f & 63;
            bool vn = (nc + n) < N_;
            sa[f] = vn ? a[((size_t)t * N_ + nc + n) * K_ + k] * invn[t * N_ + nc + n] : 0.f;
            // same f decomposed as [c][n2]
            int c = f >> 6, n2 = f & 63;
            sx[c * 65 + n2] = ((nc + n2) < N_) ? x[((size_t)t * C_ + c0 + c) * N_ + nc + n2] : 0.f;
        }
        __syncthreads();
        for (int n = 0; n < 64; ++n) {
            float xv = sx[cl * 65 + n];
            const float4* ap = reinterpret_cast<const float4*>(&sa[n * 64 + kg * 16]);
            #pragma unroll
            for (int j = 0; j < 4; ++j) {
                float4 a4 = ap[j];
                acc[j*4+0] = fmaf(a4.x, xv, acc[j*4+0]);
                acc[j*4+1] = fmaf(a4.y, xv, acc[j*4+1]);
                acc[j*4+2] = fmaf(a4.z, xv, acc[j*4+2]);
                acc[j*4+3] = fmaf(a4.w, xv, acc[j*4+3]);
            }
        }
        __syncthreads();
    }
    #pragma unroll
    for (int i = 0; i < 16; ++i) {
        int k = kg * 16 + i;
        float v = acc[i] - asum[t * 64 + k] * cent[k * 512 + c0 + cl];
        vlad[((size_t)t * 64 + k) * 512 + c0 + cl] = v;
    }
}

// per-(t,k): inv_intra and contribution to global norm:  sum_c (v*inv)^2 = s*inv^2
__global__ void k_intra(const float* __restrict__ vlad, float* __restrict__ inv_intra,
                        float* __restrict__ g) {
    int w = blockIdx.x * 4 + (threadIdx.x >> 6);  // 0..1919 = t*64+k
    int lane = threadIdx.x & 63;
    const float* vp = vlad + (size_t)w * 512 + lane;
    float s = 0.f;
    #pragma unroll
    for (int j = 0; j < 8; ++j) { float v = vp[j * 64]; s = fmaf(v, v, s); }
    s = wave_sum(s);
    float inv = 1.0f / fmaxf(sqrtf(s), EPSV);
    if (lane == 0) { inv_intra[w] = inv; g[w] = s * inv * inv; }
}

__global__ void k_global(const float* __restrict__ g, float* __restrict__ inv_g) {
    int t = threadIdx.x;
    if (t < T_) {
        float s = 0.f;
        for (int k = 0; k < 64; ++k) s += g[t * 64 + k];
        inv_g[t] = 1.0f / fmaxf(sqrtf(s), EPSV);
    }
}

// out[k*512+c] = sum_t vlad[t,k,c] * inv_intra[t,k] * inv_g[t]
__global__ void k_out(const float* __restrict__ vlad, const float* __restrict__ inv_intra,
                      const float* __restrict__ inv_g, float* __restrict__ out) {
    int idx = blockIdx.x * 256 + threadIdx.x;  // 0..32767
    int k = idx >> 9;
    float s = 0.f;
    #pragma unroll 5
    for (int t = 0; t < T_; ++t)
        s += vlad[(size_t)t * 32768 + idx] * inv_intra[t * 64 + k] * inv_g[t];
    out[idx] = s;
}

extern "C" void kernel_launch(void* const* d_in, const int* in_sizes, int n_in,
                              void* d_out, int out_size, void* d_ws, size_t ws_size,
                              hipStream_t stream) {
    const float* x    = (const float*)d_in[0];   // 30*512*784
    const float* cent = (const float*)d_in[1];   // 64*512
    const float* w    = (const float*)d_in[2];   // 64*512
    const float* b    = (const float*)d_in[3];   // 64
    float* out = (float*)d_out;                  // 32768

    float* ws = (float*)d_ws;
    float* wT        = ws;                       // 32768
    float* invn      = wT + 32768;               // 23520
    float* a         = invn + 23520;             // 30*784*64 = 1505280
    float* asum      = a + 1505280;              // 1920
    float* vlad      = asum + 1920;              // 30*64*512 = 983040
    float* inv_intra = vlad + 983040;            // 1920
    float* g         = inv_intra + 1920;         // 1920
    float* inv_g     = g + 1920;                 // 30
    // total ~2.55M floats ~= 9.8 MB

    k_transpose_w<<<128, 256, 0, stream>>>(w, wT);
    k_invnorm<<<dim3(4, T_), 256, 0, stream>>>(x, invn);
    k_assign<<<dim3(13, T_), 256, 0, stream>>>(x, wT, b, invn, a);
    k_asum<<<T_, 256, 0, stream>>>(a, asum);
    k_vlad<<<dim3(8, T_), 256, 0, stream>>>(x, a, invn, asum, cent, vlad);
    k_intra<<<480, 256, 0, stream>>>(vlad, inv_intra, g);
    k_global<<<1, 64, 0, stream>>>(g, inv_g);
    k_out<<<128, 256, 0, stream>>>(vlad, inv_intra, inv_g, out);
}

// Round 2
// 292.840 us; speedup vs baseline: 1.5564x; 1.5564x over previous
//
#include <hip/hip_runtime.h>
#include <math.h>

#define T_ 30
#define C_ 512
#define N_ 784     // 28*28
#define NP_ 832    // padded n (13 tiles of 64)
#define K_ 64
#define EPSV 1e-12f

typedef __attribute__((ext_vector_type(8))) short bf16x8;
typedef __attribute__((ext_vector_type(4))) float f32x4;

__device__ __forceinline__ float wave_sum(float v) {
    #pragma unroll
    for (int m = 32; m >= 1; m >>= 1) v += __shfl_xor(v, m, 64);
    return v;
}
__device__ __forceinline__ float wave_max(float v) {
    #pragma unroll
    for (int m = 32; m >= 1; m >>= 1) v = fmaxf(v, __shfl_xor(v, m, 64));
    return v;
}
__device__ __forceinline__ unsigned short f2bf(float f) {
    union { float f; unsigned int u; } v; v.f = f;
    unsigned int r = (v.u + 0x7FFFu + ((v.u >> 16) & 1u)) >> 16;  // RNE
    return (unsigned short)r;
}

// wT[c][k] = w[k][c]
__global__ void k_transpose_w(const float* __restrict__ w, float* __restrict__ wT) {
    int idx = blockIdx.x * 256 + threadIdx.x;  // k*512+c
    int k = idx >> 9, c = idx & 511;
    wT[c * 64 + k] = w[idx];
}

// invn[t][n] = 1/max(||x[t,:,n]||, eps)   grid (13, 30)
__global__ void k_invnorm(const float* __restrict__ x, float* __restrict__ invn) {
    __shared__ float red[4][64];
    int t = blockIdx.y;
    int n0 = blockIdx.x * 64;
    int nl = threadIdx.x & 63, cg = threadIdx.x >> 6;
    int n = n0 + nl;
    float s = 0.f;
    if (n < N_) {
        const float* xp = x + (size_t)(t * C_ + cg * 128) * N_ + n;
        #pragma unroll 8
        for (int c = 0; c < 128; ++c) { float v = xp[(size_t)c * N_]; s = fmaf(v, v, s); }
    }
    red[cg][nl] = s;
    __syncthreads();
    if (threadIdx.x < 64 && n0 + (int)threadIdx.x < N_) {
        float t4 = red[0][threadIdx.x] + red[1][threadIdx.x] + red[2][threadIdx.x] + red[3][threadIdx.x];
        invn[t * N_ + n0 + threadIdx.x] = 1.0f / fmaxf(sqrtf(t4), EPSV);
    }
}

// logits + softmax + aT(bf16, ahat=a*invn) + asum.  grid (13, 30), 256 thr.
// lane = n (coalesced x), W rows via uniform s_load, 64 acc/lane, 4-way c-split.
__global__ __launch_bounds__(256) void k_assign(
    const float* __restrict__ x, const float* __restrict__ wT,
    const float* __restrict__ b, const float* __restrict__ invn,
    unsigned short* __restrict__ aT, float* __restrict__ asum)
{
    __shared__ float red[64 * 65];   // [n][k] pad
    int t = blockIdx.y;
    int n0 = blockIdx.x * 64;
    int tid = threadIdx.x;
    int w = tid >> 6, lane = tid & 63;
    int n = n0 + lane;
    bool valid = n < N_;

    for (int i = tid; i < 64 * 65; i += 256) red[i] = 0.f;
    __syncthreads();

    float acc[64];
    #pragma unroll
    for (int k = 0; k < 64; ++k) acc[k] = 0.f;

    const float* xcol = x + (size_t)t * C_ * N_ + n;
    int c0 = w * 128;
    #pragma unroll 2
    for (int c = c0; c < c0 + 128; ++c) {
        float xv = valid ? xcol[(size_t)c * N_] : 0.f;
        const float4* w4 = reinterpret_cast<const float4*>(wT + (c << 6));  // uniform -> s_load
        #pragma unroll
        for (int j = 0; j < 16; ++j) {
            float4 wv = w4[j];
            acc[j*4+0] = fmaf(wv.x, xv, acc[j*4+0]);
            acc[j*4+1] = fmaf(wv.y, xv, acc[j*4+1]);
            acc[j*4+2] = fmaf(wv.z, xv, acc[j*4+2]);
            acc[j*4+3] = fmaf(wv.w, xv, acc[j*4+3]);
        }
    }
    // cross-wave reduce (c-split) via LDS atomics; bank = (lane+k)%32, conflict-free
    #pragma unroll
    for (int k = 0; k < 64; ++k) atomicAdd(&red[lane * 65 + k], acc[k]);
    __syncthreads();

    // softmax: wave w handles rows n_l = w*16..+15, lane = k
    float bk = b[lane];
    float ps = 0.f;
    for (int nn = 0; nn < 16; ++nn) {
        int n_l = w * 16 + nn;
        int ng = n0 + n_l;
        bool v_ok = ng < N_;
        float iv = v_ok ? invn[t * N_ + ng] : 0.f;
        float lg = fmaf(red[n_l * 65 + lane], iv, bk);
        float m = wave_max(lg);
        float e = __expf(lg - m);
        float s = wave_sum(e);
        float a = e / s;
        ps += v_ok ? a : 0.f;
        unsigned short ab = v_ok ? f2bf(a * iv) : (unsigned short)0;
        aT[((size_t)t * 64 + lane) * NP_ + ng] = ab;
    }
    atomicAdd(&asum[t * 64 + lane], ps);
}

// vlad[t][k][c] = sum_n ahat[k][n]*x[c][n] - asum[k]*cent[k][c]   (bf16 MFMA)
// grid (8, 30): c-block 64; 4 waves split the 25 n-ksteps; LDS-atomic reduce.
__global__ __launch_bounds__(256) void k_vlad(
    const float* __restrict__ x, const unsigned short* __restrict__ aT,
    const float* __restrict__ asum, const float* __restrict__ cent,
    float* __restrict__ vlad)
{
    __shared__ float sred[64 * 65];
    int t = blockIdx.y, cb = blockIdx.x;
    int tid = threadIdx.x;
    int w = tid >> 6, L = tid & 63;
    int lid = L & 15, quad = L >> 4;

    for (int i = tid; i < 64 * 65; i += 256) sred[i] = 0.f;
    __syncthreads();

    f32x4 acc[4][4];
    #pragma unroll
    for (int mt = 0; mt < 4; ++mt)
        #pragma unroll
        for (int nt = 0; nt < 4; ++nt)
            #pragma unroll
            for (int r = 0; r < 4; ++r) acc[mt][nt][r] = 0.f;

    for (int s = w; s < 25; s += 4) {
        int nb0 = s * 32;
        bf16x8 af[4];
        #pragma unroll
        for (int mt = 0; mt < 4; ++mt) {
            const unsigned short* ap = aT + ((size_t)t * 64 + mt * 16 + lid) * NP_ + nb0 + quad * 8;
            af[mt] = *reinterpret_cast<const bf16x8*>(ap);
        }
        int nb = nb0 + quad * 8;
        if (nb > 776) nb = 776;   // clamp: those lanes' aT entries are 0, value irrelevant
        bf16x8 bfr[4];
        #pragma unroll
        for (int nt = 0; nt < 4; ++nt) {
            int c = cb * 64 + nt * 16 + lid;
            const float* xp = x + (size_t)(t * C_ + c) * N_ + nb;
            float4 x0 = *reinterpret_cast<const float4*>(xp);
            float4 x1 = *reinterpret_cast<const float4*>(xp + 4);
            bf16x8 bb;
            bb[0] = (short)f2bf(x0.x); bb[1] = (short)f2bf(x0.y);
            bb[2] = (short)f2bf(x0.z); bb[3] = (short)f2bf(x0.w);
            bb[4] = (short)f2bf(x1.x); bb[5] = (short)f2bf(x1.y);
            bb[6] = (short)f2bf(x1.z); bb[7] = (short)f2bf(x1.w);
            bfr[nt] = bb;
        }
        #pragma unroll
        for (int mt = 0; mt < 4; ++mt)
            #pragma unroll
            for (int nt = 0; nt < 4; ++nt)
                acc[mt][nt] = __builtin_amdgcn_mfma_f32_16x16x32_bf16(af[mt], bfr[nt], acc[mt][nt], 0, 0, 0);
    }
    #pragma unroll
    for (int mt = 0; mt < 4; ++mt)
        #pragma unroll
        for (int nt = 0; nt < 4; ++nt)
            #pragma unroll
            for (int r = 0; r < 4; ++r)
                atomicAdd(&sred[(mt * 16 + quad * 4 + r) * 65 + nt * 16 + lid], acc[mt][nt][r]);
    __syncthreads();

    int kr = tid >> 2;
    int cc0 = (tid & 3) * 16;
    float as = asum[t * 64 + kr];
    #pragma unroll
    for (int j = 0; j < 16; ++j) {
        int cc = cc0 + j;
        float v = sred[kr * 65 + cc] - as * cent[kr * 512 + cb * 64 + cc];
        vlad[((size_t)t * 64 + kr) * 512 + cb * 64 + cc] = v;
    }
}

__global__ void k_intra(const float* __restrict__ vlad, float* __restrict__ inv_intra,
                        float* __restrict__ g) {
    int w = blockIdx.x * 4 + (threadIdx.x >> 6);  // t*64+k
    int lane = threadIdx.x & 63;
    const float* vp = vlad + (size_t)w * 512 + lane;
    float s = 0.f;
    #pragma unroll
    for (int j = 0; j < 8; ++j) { float v = vp[j * 64]; s = fmaf(v, v, s); }
    s = wave_sum(s);
    float inv = 1.0f / fmaxf(sqrtf(s), EPSV);
    if (lane == 0) { inv_intra[w] = inv; g[w] = s * inv * inv; }
}

__global__ void k_global(const float* __restrict__ g, float* __restrict__ inv_g) {
    int t = threadIdx.x;
    if (t < T_) {
        float s = 0.f;
        for (int k = 0; k < 64; ++k) s += g[t * 64 + k];
        inv_g[t] = 1.0f / fmaxf(sqrtf(s), EPSV);
    }
}

__global__ void k_out(const float* __restrict__ vlad, const float* __restrict__ inv_intra,
                      const float* __restrict__ inv_g, float* __restrict__ out) {
    int idx = blockIdx.x * 256 + threadIdx.x;  // k*512+c
    int k = idx >> 9;
    float s = 0.f;
    #pragma unroll 5
    for (int t = 0; t < T_; ++t)
        s += vlad[(size_t)t * 32768 + idx] * inv_intra[t * 64 + k] * inv_g[t];
    out[idx] = s;
}

extern "C" void kernel_launch(void* const* d_in, const int* in_sizes, int n_in,
                              void* d_out, int out_size, void* d_ws, size_t ws_size,
                              hipStream_t stream) {
    const float* x    = (const float*)d_in[0];   // 30*512*784
    const float* cent = (const float*)d_in[1];   // 64*512
    const float* w    = (const float*)d_in[2];   // 64*512
    const float* b    = (const float*)d_in[3];   // 64
    float* out = (float*)d_out;

    float* ws = (float*)d_ws;
    float* wT        = ws;                        // 32768
    float* invn      = wT + 32768;                // 23520
    float* asum      = invn + 23520;              // 1920
    unsigned short* aT = (unsigned short*)(asum + 1920);  // 30*64*832 ushort = 798720 floats
    float* vlad      = asum + 1920 + 798720;      // 983040
    float* inv_intra = vlad + 983040;             // 1920
    float* g         = inv_intra + 1920;          // 1920
    float* inv_g     = g + 1920;                  // 30
    // total ~7.4 MB

    k_transpose_w<<<128, 256, 0, stream>>>(w, wT);
    k_invnorm<<<dim3(13, T_), 256, 0, stream>>>(x, invn);
    hipMemsetAsync(asum, 0, 1920 * sizeof(float), stream);
    k_assign<<<dim3(13, T_), 256, 0, stream>>>(x, wT, b, invn, aT, asum);
    k_vlad<<<dim3(8, T_), 256, 0, stream>>>(x, aT, asum, cent, vlad);
    k_intra<<<480, 256, 0, stream>>>(vlad, inv_intra, g);
    k_global<<<1, 64, 0, stream>>>(g, inv_g);
    k_out<<<128, 256, 0, stream>>>(vlad, inv_intra, inv_g, out);
}

// Round 3
// 161.121 us; speedup vs baseline: 2.8288x; 1.8175x over previous
//
#include <hip/hip_runtime.h>
#include <math.h>

#define T_ 30
#define C_ 512
#define N_ 784     // 28*28
#define NP_ 832    // padded n (13 tiles of 64)
#define EPSV 1e-12f

typedef __attribute__((ext_vector_type(8))) short bf16x8;
typedef __attribute__((ext_vector_type(4))) float f32x4;

__device__ __forceinline__ unsigned short f2bf(float f) {
    union { float f; unsigned int u; } v; v.f = f;
    unsigned int r = (v.u + 0x7FFFu + ((v.u >> 16) & 1u)) >> 16;  // RNE
    return (unsigned short)r;
}
__device__ __forceinline__ float bf2f(unsigned short h) {
    union { unsigned int u; float f; } v; v.u = ((unsigned int)h) << 16;
    return v.f;
}

// wh/wl: split-precision bf16 of w, layout [k][c] (c contiguous)
__global__ void k_prep(const float* __restrict__ w, unsigned short* __restrict__ wh,
                       unsigned short* __restrict__ wl) {
    int idx = blockIdx.x * 256 + threadIdx.x;  // 0..32767
    float v = w[idx];
    unsigned short h = f2bf(v);
    wh[idx] = h;
    wl[idx] = f2bf(v - bf2f(h));
}

// Fused: invnorm + logits (3-product bf16 MFMA) + softmax + aT(bf16 a*invn) + asum
// grid (13, 30), 256 threads. Block covers 64 n, all 512 c in 4 chunks of 128.
__global__ __launch_bounds__(256) void k_assign(
    const float* __restrict__ x, const unsigned short* __restrict__ wh,
    const unsigned short* __restrict__ wl, const float* __restrict__ b,
    unsigned short* __restrict__ aT, float* __restrict__ asum)
{
    __shared__ __align__(16) unsigned short xhT[64 * 130];  // [n][c] bf16-hi, pad->130
    __shared__ __align__(16) unsigned short xlT[64 * 130];  // [n][c] bf16-lo
    __shared__ float bloc[64], invl[64], asl[64], ssred[4][64];

    int t = blockIdx.y, n0 = blockIdx.x * 64;
    int tid = threadIdx.x;
    int w = tid >> 6, L = tid & 63, lid = L & 15, quad = L >> 4;

    if (tid < 64) { bloc[tid] = b[tid]; asl[tid] = 0.f; }

    // staging decomposition: thread -> (n-quad li, c-row crg)
    int li = tid & 15;
    int crg = tid >> 4;
    int nbase = n0 + li * 4;
    float ss0 = 0.f, ss1 = 0.f, ss2 = 0.f, ss3 = 0.f;

    f32x4 acc[4];
    #pragma unroll
    for (int mt = 0; mt < 4; ++mt)
        #pragma unroll
        for (int r = 0; r < 4; ++r) acc[mt][r] = 0.f;

    for (int ch = 0; ch < 4; ++ch) {
        int c0 = ch * 128;
        #pragma unroll
        for (int p = 0; p < 8; ++p) {
            int cl = p * 16 + crg;
            const float* xp = x + ((size_t)t * C_ + c0 + cl) * N_ + nbase;
            float v0, v1, v2, v3;
            if (nbase + 3 < N_) {
                float4 q = *reinterpret_cast<const float4*>(xp);
                v0 = q.x; v1 = q.y; v2 = q.z; v3 = q.w;
            } else {
                v0 = (nbase + 0 < N_) ? xp[0] : 0.f;
                v1 = (nbase + 1 < N_) ? xp[1] : 0.f;
                v2 = (nbase + 2 < N_) ? xp[2] : 0.f;
                v3 = (nbase + 3 < N_) ? xp[3] : 0.f;
            }
            ss0 = fmaf(v0, v0, ss0); ss1 = fmaf(v1, v1, ss1);
            ss2 = fmaf(v2, v2, ss2); ss3 = fmaf(v3, v3, ss3);
            float vv[4] = {v0, v1, v2, v3};
            #pragma unroll
            for (int j = 0; j < 4; ++j) {
                unsigned short h = f2bf(vv[j]);
                xhT[(li * 4 + j) * 130 + cl] = h;
                xlT[(li * 4 + j) * 130 + cl] = f2bf(vv[j] - bf2f(h));
            }
        }
        __syncthreads();
        #pragma unroll
        for (int ks = 0; ks < 4; ++ks) {
            int cl = ks * 32 + quad * 8;
            bf16x8 bh = *reinterpret_cast<const bf16x8*>(&xhT[(w * 16 + lid) * 130 + cl]);
            bf16x8 blo = *reinterpret_cast<const bf16x8*>(&xlT[(w * 16 + lid) * 130 + cl]);
            int cg = c0 + cl;
            #pragma unroll
            for (int mt = 0; mt < 4; ++mt) {
                bf16x8 ah = *reinterpret_cast<const bf16x8*>(wh + (mt * 16 + lid) * 512 + cg);
                bf16x8 al = *reinterpret_cast<const bf16x8*>(wl + (mt * 16 + lid) * 512 + cg);
                acc[mt] = __builtin_amdgcn_mfma_f32_16x16x32_bf16(ah, bh, acc[mt], 0, 0, 0);
                acc[mt] = __builtin_amdgcn_mfma_f32_16x16x32_bf16(ah, blo, acc[mt], 0, 0, 0);
                acc[mt] = __builtin_amdgcn_mfma_f32_16x16x32_bf16(al, bh, acc[mt], 0, 0, 0);
            }
        }
        __syncthreads();
    }

    // sumsq: reduce over the 4 c-row groups within wave (quad axis), then across waves
    ss0 += __shfl_xor(ss0, 16, 64); ss0 += __shfl_xor(ss0, 32, 64);
    ss1 += __shfl_xor(ss1, 16, 64); ss1 += __shfl_xor(ss1, 32, 64);
    ss2 += __shfl_xor(ss2, 16, 64); ss2 += __shfl_xor(ss2, 32, 64);
    ss3 += __shfl_xor(ss3, 16, 64); ss3 += __shfl_xor(ss3, 32, 64);
    if (quad == 0) {
        ssred[w][li * 4 + 0] = ss0; ssred[w][li * 4 + 1] = ss1;
        ssred[w][li * 4 + 2] = ss2; ssred[w][li * 4 + 3] = ss3;
    }
    __syncthreads();
    if (tid < 64) {
        float s = ssred[0][tid] + ssred[1][tid] + ssred[2][tid] + ssred[3][tid];
        invl[tid] = 1.0f / fmaxf(sqrtf(s), EPSV);
    }
    __syncthreads();

    // softmax over k. Lane holds n = n0 + w*16 + lid, k = mt*16 + quad*4 + r.
    int n_lane = n0 + w * 16 + lid;
    bool valid = n_lane < N_;
    float inv = valid ? invl[w * 16 + lid] : 0.f;
    float lg[16];
    float mx = -1e30f;
    #pragma unroll
    for (int mt = 0; mt < 4; ++mt)
        #pragma unroll
        for (int r = 0; r < 4; ++r) {
            float v = fmaf(acc[mt][r], inv, bloc[mt * 16 + quad * 4 + r]);
            lg[mt * 4 + r] = v;
            mx = fmaxf(mx, v);
        }
    mx = fmaxf(mx, __shfl_xor(mx, 16, 64));
    mx = fmaxf(mx, __shfl_xor(mx, 32, 64));
    float se = 0.f;
    #pragma unroll
    for (int u = 0; u < 16; ++u) { lg[u] = __expf(lg[u] - mx); se += lg[u]; }
    se += __shfl_xor(se, 16, 64);
    se += __shfl_xor(se, 32, 64);
    float rs = 1.0f / se;

    size_t base = (size_t)t * 64 * NP_ + n_lane;
    #pragma unroll
    for (int mt = 0; mt < 4; ++mt)
        #pragma unroll
        for (int r = 0; r < 4; ++r) {
            int k = mt * 16 + quad * 4 + r;
            float a = lg[mt * 4 + r] * rs;
            aT[base + (size_t)k * NP_] = valid ? f2bf(a * inv) : (unsigned short)0;
            float ak = valid ? a : 0.f;
            ak += __shfl_xor(ak, 1, 64); ak += __shfl_xor(ak, 2, 64);
            ak += __shfl_xor(ak, 4, 64); ak += __shfl_xor(ak, 8, 64);
            if (lid == 0) atomicAdd(&asl[k], ak);
        }
    __syncthreads();
    if (tid < 64) atomicAdd(&asum[t * 64 + tid], asl[tid]);
}

// vlad[t][k][c] = sum_n ahat[k][n]*x[c][n] - asum[k]*cent[k][c]
// grid (8, 30). Wave w owns c-strip cb*64 + w*16 + lid; loops all 25 n-steps. No LDS.
__global__ __launch_bounds__(256) void k_vlad(
    const float* __restrict__ x, const unsigned short* __restrict__ aT,
    const float* __restrict__ asum, const float* __restrict__ cent,
    float* __restrict__ vlad)
{
    int t = blockIdx.y, cb = blockIdx.x;
    int tid = threadIdx.x;
    int w = tid >> 6, L = tid & 63, lid = L & 15, quad = L >> 4;
    int c = cb * 64 + w * 16 + lid;

    f32x4 acc[4];
    #pragma unroll
    for (int mt = 0; mt < 4; ++mt)
        #pragma unroll
        for (int r = 0; r < 4; ++r) acc[mt][r] = 0.f;

    const float* xrow = x + ((size_t)t * C_ + c) * N_;
    const unsigned short* ab = aT + (size_t)t * 64 * NP_;

    for (int s = 0; s < 25; ++s) {
        int nb0 = s * 32;
        int nb = nb0 + quad * 8;
        if (nb > N_ - 8) nb = N_ - 8;  // clamped lanes multiply aT==0 entries
        float4 x0 = *reinterpret_cast<const float4*>(xrow + nb);
        float4 x1 = *reinterpret_cast<const float4*>(xrow + nb + 4);
        bf16x8 bb;
        bb[0] = (short)f2bf(x0.x); bb[1] = (short)f2bf(x0.y);
        bb[2] = (short)f2bf(x0.z); bb[3] = (short)f2bf(x0.w);
        bb[4] = (short)f2bf(x1.x); bb[5] = (short)f2bf(x1.y);
        bb[6] = (short)f2bf(x1.z); bb[7] = (short)f2bf(x1.w);
        #pragma unroll
        for (int mt = 0; mt < 4; ++mt) {
            bf16x8 af = *reinterpret_cast<const bf16x8*>(
                ab + (size_t)(mt * 16 + lid) * NP_ + nb0 + quad * 8);
            acc[mt] = __builtin_amdgcn_mfma_f32_16x16x32_bf16(af, bb, acc[mt], 0, 0, 0);
        }
    }
    #pragma unroll
    for (int mt = 0; mt < 4; ++mt)
        #pragma unroll
        for (int r = 0; r < 4; ++r) {
            int k = mt * 16 + quad * 4 + r;
            float v = acc[mt][r] - asum[t * 64 + k] * cent[k * 512 + c];
            vlad[((size_t)t * 64 + k) * 512 + c] = v;
        }
}

__global__ void k_intra(const float* __restrict__ vlad, float* __restrict__ inv_intra,
                        float* __restrict__ g) {
    int w = blockIdx.x * 4 + (threadIdx.x >> 6);  // t*64+k
    int lane = threadIdx.x & 63;
    const float* vp = vlad + (size_t)w * 512 + lane;
    float s = 0.f;
    #pragma unroll
    for (int j = 0; j < 8; ++j) { float v = vp[j * 64]; s = fmaf(v, v, s); }
    #pragma unroll
    for (int m = 32; m >= 1; m >>= 1) s += __shfl_xor(s, m, 64);
    float inv = 1.0f / fmaxf(sqrtf(s), EPSV);
    if (lane == 0) { inv_intra[w] = inv; g[w] = s * inv * inv; }
}

__global__ void k_global(const float* __restrict__ g, float* __restrict__ inv_g) {
    int t = threadIdx.x;
    if (t < T_) {
        float s = 0.f;
        for (int k = 0; k < 64; ++k) s += g[t * 64 + k];
        inv_g[t] = 1.0f / fmaxf(sqrtf(s), EPSV);
    }
}

__global__ void k_out(const float* __restrict__ vlad, const float* __restrict__ inv_intra,
                      const float* __restrict__ inv_g, float* __restrict__ out) {
    int idx = blockIdx.x * 256 + threadIdx.x;  // k*512+c
    int k = idx >> 9;
    float s = 0.f;
    #pragma unroll 5
    for (int t = 0; t < T_; ++t)
        s += vlad[(size_t)t * 32768 + idx] * inv_intra[t * 64 + k] * inv_g[t];
    out[idx] = s;
}

extern "C" void kernel_launch(void* const* d_in, const int* in_sizes, int n_in,
                              void* d_out, int out_size, void* d_ws, size_t ws_size,
                              hipStream_t stream) {
    const float* x    = (const float*)d_in[0];   // 30*512*784
    const float* cent = (const float*)d_in[1];   // 64*512
    const float* w    = (const float*)d_in[2];   // 64*512
    const float* b    = (const float*)d_in[3];   // 64
    float* out = (float*)d_out;

    float* ws = (float*)d_ws;
    unsigned short* wh = (unsigned short*)ws;          // 32768 us
    unsigned short* wl = wh + 32768;                   // 32768 us
    float* asum = (float*)(wl + 32768);                // 1920 f
    unsigned short* aT = (unsigned short*)(asum + 1920);  // 30*64*832 us
    float* vlad = (float*)(aT + (size_t)T_ * 64 * NP_);   // 983040 f
    float* inv_intra = vlad + 983040;                  // 1920
    float* g         = inv_intra + 1920;               // 1920
    float* inv_g     = g + 1920;                       // 30

    k_prep<<<128, 256, 0, stream>>>(w, wh, wl);
    hipMemsetAsync(asum, 0, 1920 * sizeof(float), stream);
    k_assign<<<dim3(13, T_), 256, 0, stream>>>(x, wh, wl, b, aT, asum);
    k_vlad<<<dim3(8, T_), 256, 0, stream>>>(x, aT, asum, cent, vlad);
    k_intra<<<480, 256, 0, stream>>>(vlad, inv_intra, g);
    k_global<<<1, 64, 0, stream>>>(g, inv_g);
    k_out<<<128, 256, 0, stream>>>(vlad, inv_intra, inv_g, out);
}